// Round 3
// baseline (20759.415 us; speedup 1.0000x reference)
//
#include <hip/hip_runtime.h>
#include <math.h>

#define BB 2048
#define DD 512
#define CC 128
#define TT 151
#define G3 1536  // 3*D

typedef __bf16 bf16x8 __attribute__((ext_vector_type(8)));
typedef float f32x4 __attribute__((ext_vector_type(4)));

// ---------------- precompute kernels ----------------

// WihT[k*G3 + j] = Wih[j*DD + k]  (for E build)
__global__ void k_transpose_wih(const float* __restrict__ Wih, float* __restrict__ WihT) {
    int idx = blockIdx.x * 256 + threadIdx.x;
    if (idx < G3 * DD) {
        int j = idx / DD, k = idx - j * DD;
        WihT[k * G3 + j] = Wih[idx];
    }
}

// W_hh split-bf16 B-fragments, COLUMN-SPLIT layout across block pairs.
// [s 0..1][w 0..7][kt 0..15][tile 0..5 (g*2+tl)][part hi/lo][lane 0..63][j 0..7]
//   jcol = g*512 + s*256 + w*32 + tl*16 + (lane&15),  k = kt*32 + (lane>>4)*8 + j
__global__ void k_pack_whh_frag(const float* __restrict__ Whh, __bf16* __restrict__ out) {
    int idx = blockIdx.x * 256 + threadIdx.x;  // 786432
    if (idx >= 786432) return;
    int j8 = idx & 7;
    int lane = (idx >> 3) & 63;
    int rest = idx >> 9;          // 0..1535
    int tile = rest % 6;
    int kt = (rest / 6) % 16;
    int w = (rest / 96) % 8;
    int s = rest / 768;
    int g = tile >> 1, tl = tile & 1;
    int jcol = g * 512 + s * 256 + w * 32 + tl * 16 + (lane & 15);
    int k = kt * 32 + (lane >> 4) * 8 + j8;
    float v = Whh[jcol * DD + k];
    __bf16 hi = (__bf16)v;
    __bf16 lo = (__bf16)(v - (float)hi);
    size_t base = (size_t)((((s * 8 + w) * 16 + kt) * 6 + tile) * 2) * 512 + lane * 8 + j8;
    out[base] = hi;
    out[base + 512] = lo;
}

// W_proj split-bf16 B-fragments, K-HALF split: [s][w][kt 0..7][part][lane][8]
//   c = w*16 + (lane&15),  k = s*256 + kt*32 + (lane>>4)*8 + j
__global__ void k_pack_wp_frag(const float* __restrict__ Wproj, __bf16* __restrict__ out) {
    int idx = blockIdx.x * 256 + threadIdx.x;  // 65536
    if (idx >= 65536) return;
    int j = idx & 7;
    int lane = (idx >> 3) & 63;
    int rest = idx >> 9;          // 0..127
    int kt = rest % 8;
    int w = (rest / 8) % 8;
    int s = rest / 64;
    int c = w * 16 + (lane & 15);
    int k = s * 256 + kt * 32 + (lane >> 4) * 8 + j;
    float v = Wproj[c * DD + k];
    __bf16 hi = (__bf16)v;
    __bf16 lo = (__bf16)(v - (float)hi);
    size_t base = (size_t)(((s * 8 + w) * 8 + kt) * 2) * 512 + lane * 8 + j;
    out[base] = hi;
    out[base + 512] = lo;
}

// E[c][j] = b_ih[j] + (j<1024 ? b_hh[j] : 0) + sum_k embed[c][k]*W_ih[j][k]; row 128 = biases only
__global__ void k_build_E(const float* __restrict__ embed, const float* __restrict__ WihT,
                          const float* __restrict__ b_ih, const float* __restrict__ b_hh,
                          float* __restrict__ E) {
    __shared__ float emb[16][DD];
    const int t = threadIdx.x;
    const int j = blockIdx.x * 256 + t;
    const int c0 = blockIdx.y * 16;
    for (int i = 0; i < 16; i++) {
        int c = c0 + i;
        for (int k = t; k < DD; k += 256)
            emb[i][k] = (c < CC) ? embed[c * DD + k] : 0.0f;
    }
    __syncthreads();
    float acc[16];
#pragma unroll
    for (int i = 0; i < 16; i++) acc[i] = 0.0f;
    for (int k = 0; k < DD; k++) {
        float wv = WihT[k * G3 + j];
#pragma unroll
        for (int i = 0; i < 16; i++) acc[i] = fmaf(emb[i][k], wv, acc[i]);
    }
    float bj = b_ih[j] + (j < 1024 ? b_hh[j] : 0.0f);
    for (int i = 0; i < 16; i++) {
        int c = c0 + i;
        if (c <= CC) E[(size_t)c * G3 + j] = acc[i] + bj;
    }
}

// ---------------- main persistent GRU kernel ----------------

__device__ __forceinline__ float fast_sigmoid(float x) {
    return __builtin_amdgcn_rcpf(1.0f + __expf(-x));
}
__device__ __forceinline__ float fast_tanh(float x) {
    x = fminf(10.0f, fmaxf(-10.0f, x));
    float e = __expf(2.0f * x);
    return (e - 1.0f) * __builtin_amdgcn_rcpf(e + 1.0f);
}

// COLUMN-SPLIT pair design: grid=256, blocks (pair, s) with s in {0,1}.
// Both blocks of a pair own the SAME 16 batch rows; block s computes gh columns
// for d in [s*256, s*256+256) of each gate (half the W_hh stream = 1.57 MB/step)
// and the k-half partial logits. Per step the pair exchanges h-halves (16 KB)
// and partial logits (8 KB) via agent-scope atomics + a flag handshake.
// REQUIRES all 256 blocks co-resident: LDS > 80 KB forces 1 block/CU, grid == #CUs.
__global__ __launch_bounds__(512, 2) void k_gru(
    const float* __restrict__ feat, const __bf16* __restrict__ Whf,
    const __bf16* __restrict__ Wpf, const float* __restrict__ b_proj,
    const float* __restrict__ b_hh, const float* __restrict__ Ep,
    unsigned int* xh, float* xl, int* flags,
    float* __restrict__ out) {
    __shared__ __align__(16) __bf16 h_hi[16][520];  // 16.25 KB, +8 col pad
    __shared__ __align__(16) __bf16 h_lo[16][520];  // 16.25 KB
    __shared__ float plg[16][CC];                   // 8 KB logits (partial -> full)
    __shared__ float lgbuf[16][64][10];             // 40 KB output burst buffer (own 64 cols)
    __shared__ float bpj[CC];
    __shared__ int tok_s[16];

    float* out_logits = out;                      // [B][C][T]
    float* out_tok = out + (size_t)BB * CC * TT;  // [B][T] as float

    const int t = threadIdx.x;   // 0..511
    const int w = t >> 6;        // wave 0..7
    const int lane = t & 63;
    const int col = lane & 15;
    const int quad = lane >> 4;
    const int bq = quad * 4;

    // swizzle: XCDs 0-3 host s=0 halves, 4-7 host s=1 (perf heuristic only)
    const int bid = blockIdx.x;
    const int grp = bid & 7;
    const int s = grp >> 2;
    const int pair = (bid >> 3) * 4 + (grp & 3);  // 0..127
    const int row0 = pair * 16;
    const int fl_self = pair * 2 + s;

    // ---- init: full h0 into LDS; own-half h0 into registers
    for (int i = 0; i < 16; i++) {
        float v = feat[(size_t)(row0 + i) * DD + t];
        __bf16 hi = (__bf16)v;
        h_hi[i][t] = hi;
        h_lo[i][t] = (__bf16)(v - (float)hi);
    }
    float ho[2][4];
#pragma unroll
    for (int tl = 0; tl < 2; tl++) {
        const int d = s * 256 + w * 32 + tl * 16 + col;
#pragma unroll
        for (int rg = 0; rg < 4; rg++)
            ho[tl][rg] = feat[(size_t)(row0 + bq + rg) * DD + d];
    }
    if (t < CC) bpj[t] = b_proj[t];
    if (t < 16) tok_s[t] = CC;  // start token -> E row 128 (x0 = 0)

    float bhn_t[2];
#pragma unroll
    for (int tl = 0; tl < 2; tl++)
        bhn_t[tl] = b_hh[1024 + s * 256 + w * 32 + tl * 16 + col];

    const __bf16* wseq = Whf + (size_t)(s * 8 + w) * 98304;  // 16kt*6tile*2part*512
    const __bf16* wpseq = Wpf + (size_t)(s * 8 + w) * 8192;  // 8kt*2part*512
    __syncthreads();

    for (int step = 0; step < TT; step++) {
        const int sl = step & 7;
        const int par = step & 1;
        unsigned int* xh_self = xh + ((size_t)(pair * 2 + par) * 2 + s) * 4096;
        unsigned int* xh_part = xh + ((size_t)(pair * 2 + par) * 2 + (1 - s)) * 4096;
        float* xl_self = xl + ((size_t)(pair * 2 + par) * 2 + s) * 2048;
        float* xl_part = xl + ((size_t)(pair * 2 + par) * 2 + (1 - s)) * 2048;

        // ---- P1: own-half gh = h @ W_hh^T, split-bf16 MFMA, 6 tiles
        f32x4 acc[6];
#pragma unroll
        for (int i = 0; i < 6; i++) acc[i] = (f32x4)(0.0f);
        for (int kt = 0; kt < 16; kt++) {
            bf16x8 ahi = *(const bf16x8*)&h_hi[col][kt * 32 + quad * 8];
            bf16x8 alo = *(const bf16x8*)&h_lo[col][kt * 32 + quad * 8];
            const __bf16* wk = wseq + kt * 6144;
#pragma unroll
            for (int tile = 0; tile < 6; tile++) {
                bf16x8 bhi = *(const bf16x8*)(wk + tile * 1024 + lane * 8);
                bf16x8 blo = *(const bf16x8*)(wk + tile * 1024 + 512 + lane * 8);
                acc[tile] = __builtin_amdgcn_mfma_f32_16x16x32_bf16(ahi, bhi, acc[tile], 0, 0, 0);
                acc[tile] = __builtin_amdgcn_mfma_f32_16x16x32_bf16(alo, bhi, acc[tile], 0, 0, 0);
                acc[tile] = __builtin_amdgcn_mfma_f32_16x16x32_bf16(ahi, blo, acc[tile], 0, 0, 0);
            }
        }
        __syncthreads();  // all waves done reading h

        // ---- P2: gates for own 256 d; write h_new to LDS + exchange buffer
        {
            int tk[4];
#pragma unroll
            for (int rg = 0; rg < 4; rg++) tk[rg] = tok_s[bq + rg];
#pragma unroll
            for (int tl = 0; tl < 2; tl++) {
                const int d = s * 256 + w * 32 + tl * 16 + col;
                const int dl = d - s * 256;
#pragma unroll
                for (int rg = 0; rg < 4; rg++) {
                    const int b = bq + rg;
                    const float* Er = Ep + (size_t)tk[rg] * G3 + d;
                    float rr = fast_sigmoid(acc[tl][rg] + Er[0]);
                    float zz = fast_sigmoid(acc[2 + tl][rg] + Er[512]);
                    float nn = fast_tanh(Er[1024] + rr * (acc[4 + tl][rg] + bhn_t[tl]));
                    float hv = (1.0f - zz) * nn + zz * ho[tl][rg];
                    ho[tl][rg] = hv;
                    __bf16 hi = (__bf16)hv;
                    __bf16 lo = (__bf16)(hv - (float)hi);
                    h_hi[b][d] = hi;
                    h_lo[b][d] = lo;
                    unsigned int val = ((unsigned int)__builtin_bit_cast(unsigned short, hi) << 16) |
                                       (unsigned int)__builtin_bit_cast(unsigned short, lo);
                    __hip_atomic_store(&xh_self[b * 256 + dl], val, __ATOMIC_RELAXED,
                                       __HIP_MEMORY_SCOPE_AGENT);
                }
            }
        }
        __syncthreads();  // own-half h_new in LDS for P3a

        // ---- P3a: k-half partial logits; wave w -> cols [16w,16w+16)
        {
            f32x4 accp = (f32x4)(0.0f);
            for (int ktl = 0; ktl < 8; ktl++) {
                const int kt = s * 8 + ktl;
                bf16x8 ahi = *(const bf16x8*)&h_hi[col][kt * 32 + quad * 8];
                bf16x8 alo = *(const bf16x8*)&h_lo[col][kt * 32 + quad * 8];
                const __bf16* pk = wpseq + ktl * 1024;
                bf16x8 bhi = *(const bf16x8*)(pk + lane * 8);
                bf16x8 blo = *(const bf16x8*)(pk + 512 + lane * 8);
                accp = __builtin_amdgcn_mfma_f32_16x16x32_bf16(ahi, bhi, accp, 0, 0, 0);
                accp = __builtin_amdgcn_mfma_f32_16x16x32_bf16(alo, bhi, accp, 0, 0, 0);
                accp = __builtin_amdgcn_mfma_f32_16x16x32_bf16(ahi, blo, accp, 0, 0, 0);
            }
            const int c = w * 16 + col;
#pragma unroll
            for (int rg = 0; rg < 4; rg++) {
                plg[bq + rg][c] = accp[rg];
                __hip_atomic_store(&xl_self[(bq + rg) * CC + c], accp[rg], __ATOMIC_RELAXED,
                                   __HIP_MEMORY_SCOPE_AGENT);
            }
        }
        __syncthreads();  // all exchange stores drained (barrier implies vmcnt(0))

        // ---- handshake: publish flag, spin for partner
        if (t == 0) {
            __hip_atomic_store(&flags[fl_self], step + 1, __ATOMIC_RELEASE,
                               __HIP_MEMORY_SCOPE_AGENT);
            while (__hip_atomic_load(&flags[fl_self ^ 1], __ATOMIC_ACQUIRE,
                                     __HIP_MEMORY_SCOPE_AGENT) < step + 1)
                __builtin_amdgcn_s_sleep(1);
        }
        __syncthreads();

        // ---- merge: partner h-half -> LDS; sum partials -> full logits
        for (int i = 0; i < 8; i++) {
            const int idx = t + i * 512;  // 4096
            const int b = idx >> 8, dl = idx & 255;
            unsigned int v = __hip_atomic_load(&xh_part[idx], __ATOMIC_RELAXED,
                                               __HIP_MEMORY_SCOPE_AGENT);
            h_hi[b][(1 - s) * 256 + dl] = __builtin_bit_cast(__bf16, (unsigned short)(v >> 16));
            h_lo[b][(1 - s) * 256 + dl] = __builtin_bit_cast(__bf16, (unsigned short)(v & 0xffff));
        }
        for (int i = 0; i < 4; i++) {
            const int idx = t + i * 512;  // 2048
            const int b = idx >> 7, c = idx & (CC - 1);
            float oth = __hip_atomic_load(&xl_part[idx], __ATOMIC_RELAXED,
                                          __HIP_MEMORY_SCOPE_AGENT);
            float own = plg[b][c];
            float p0 = (s == 0) ? own : oth;
            float p1 = (s == 0) ? oth : own;
            float lg = (p0 + p1) + bpj[c];  // identical bits in both blocks
            plg[b][c] = lg;
            if ((c >> 6) == s) lgbuf[b][c & 63][sl] = lg;
        }
        __syncthreads();  // full logits + partner h visible

        // ---- P3b: argmax; wave w handles rows 2w, 2w+1
        {
#pragma unroll
            for (int pass = 0; pass < 2; pass++) {
                const int r = w * 2 + pass;
                float v0 = plg[r][lane];
                float v1 = plg[r][lane + 64];
                float bv; int bi;
                if (v0 >= v1) { bv = v0; bi = lane; } else { bv = v1; bi = lane + 64; }
#pragma unroll
                for (int off = 32; off > 0; off >>= 1) {
                    float ov = __shfl_down(bv, off, 64);
                    int oi = __shfl_down(bi, off, 64);
                    if (ov > bv || (ov == bv && oi < bi)) { bv = ov; bi = oi; }
                }
                if (lane == 0) {
                    tok_s[r] = bi;
                    if (s == 0)
                        __builtin_nontemporal_store(
                            (float)bi, &out_tok[(size_t)(row0 + r) * TT + step]);
                }
            }
        }
        __syncthreads();  // tok_s + lgbuf stable

        // ---- flush own 64-col logit slice every 8 steps (nontemporal)
        if ((step & 7) == 7 || step == TT - 1) {
            const int t0 = step & ~7;
            const int cnt = step - t0 + 1;
#pragma unroll
            for (int p = 0; p < 2; p++) {
                const int pr = t + p * 512;  // 0..1023
                const int b = pr >> 6, c64 = pr & 63;
                float* dst = out_logits + ((size_t)(row0 + b) * CC + (s * 64 + c64)) * TT + t0;
                const float* src = &lgbuf[b][c64][0];
                for (int q = 0; q < cnt; q++) __builtin_nontemporal_store(src[q], &dst[q]);
            }
        }
    }
}

// ---------------- launcher ----------------

extern "C" void kernel_launch(void* const* d_in, const int* in_sizes, int n_in,
                              void* d_out, int out_size, void* d_ws, size_t ws_size,
                              hipStream_t stream) {
    const float* feat   = (const float*)d_in[0];
    const float* W_ih   = (const float*)d_in[1];
    const float* W_hh   = (const float*)d_in[2];
    const float* b_ih   = (const float*)d_in[3];
    const float* b_hh   = (const float*)d_in[4];
    const float* W_proj = (const float*)d_in[5];
    const float* b_proj = (const float*)d_in[6];
    const float* embed  = (const float*)d_in[7];
    float* out = (float*)d_out;

    float* ws = (float*)d_ws;
    float*        WihT  = ws;                              // 786432 floats
    float*        E     = ws + 786432;                     // 198144 floats
    __bf16*       Whf   = (__bf16*)(ws + 984576);          // 1572864 bf16 = 786432 slots
    __bf16*       Wpf   = (__bf16*)(ws + 1771008);         // 131072 bf16 = 65536 slots
    unsigned int* xh    = (unsigned int*)(ws + 1836544);   // 2097152 uints
    float*        xl    = ws + 3933696;                    // 1048576 floats
    int*          flags = (int*)(ws + 4982272);            // 256 ints
    // total ~19.9 MB

    hipMemsetAsync(flags, 0, 256 * sizeof(int), stream);
    hipLaunchKernelGGL(k_transpose_wih, dim3(3072), dim3(256), 0, stream, W_ih, WihT);
    hipLaunchKernelGGL(k_pack_wp_frag, dim3(256), dim3(256), 0, stream, W_proj, Wpf);
    hipLaunchKernelGGL(k_pack_whh_frag, dim3(3072), dim3(256), 0, stream, W_hh, Whf);
    hipLaunchKernelGGL(k_build_E, dim3(6, 9), dim3(256), 0, stream, embed, WihT, b_ih, b_hh, E);
    hipLaunchKernelGGL(k_gru, dim3(256), dim3(512), 0, stream,
                       feat, Whf, Wpf, b_proj, b_hh, E, xh, xl, flags, out);
}

// Round 4
// 20379.633 us; speedup vs baseline: 1.0186x; 1.0186x over previous
//
#include <hip/hip_runtime.h>
#include <math.h>

#define BB 2048
#define DD 512
#define CC 128
#define TT 151
#define G3 1536  // 3*D

typedef __bf16 bf16x8 __attribute__((ext_vector_type(8)));
typedef float f32x4 __attribute__((ext_vector_type(4)));

// ---------------- precompute kernels ----------------

// WihT[k*G3 + j] = Wih[j*DD + k]  (for E build)
__global__ void k_transpose_wih(const float* __restrict__ Wih, float* __restrict__ WihT) {
    int idx = blockIdx.x * 256 + threadIdx.x;
    if (idx < G3 * DD) {
        int j = idx / DD, k = idx - j * DD;
        WihT[k * G3 + j] = Wih[idx];
    }
}

// W_hh split-bf16 B-fragments, COLUMN-SPLIT layout across block pairs.
// [s 0..1][w 0..7][kt 0..15][tile 0..5 (g*2+tl)][part hi/lo][lane 0..63][j 0..7]
//   jcol = g*512 + s*256 + w*32 + tl*16 + (lane&15),  k = kt*32 + (lane>>4)*8 + j
__global__ void k_pack_whh_frag(const float* __restrict__ Whh, __bf16* __restrict__ out) {
    int idx = blockIdx.x * 256 + threadIdx.x;  // 786432
    if (idx >= 786432) return;
    int j8 = idx & 7;
    int lane = (idx >> 3) & 63;
    int rest = idx >> 9;          // 0..1535
    int tile = rest % 6;
    int kt = (rest / 6) % 16;
    int w = (rest / 96) % 8;
    int s = rest / 768;
    int g = tile >> 1, tl = tile & 1;
    int jcol = g * 512 + s * 256 + w * 32 + tl * 16 + (lane & 15);
    int k = kt * 32 + (lane >> 4) * 8 + j8;
    float v = Whh[jcol * DD + k];
    __bf16 hi = (__bf16)v;
    __bf16 lo = (__bf16)(v - (float)hi);
    size_t base = (size_t)((((s * 8 + w) * 16 + kt) * 6 + tile) * 2) * 512 + lane * 8 + j8;
    out[base] = hi;
    out[base + 512] = lo;
}

// W_proj split-bf16 B-fragments, K-HALF split: [s][w][kt 0..7][part][lane][8]
//   c = w*16 + (lane&15),  k = s*256 + kt*32 + (lane>>4)*8 + j
__global__ void k_pack_wp_frag(const float* __restrict__ Wproj, __bf16* __restrict__ out) {
    int idx = blockIdx.x * 256 + threadIdx.x;  // 65536
    if (idx >= 65536) return;
    int j = idx & 7;
    int lane = (idx >> 3) & 63;
    int rest = idx >> 9;          // 0..127
    int kt = rest % 8;
    int w = (rest / 8) % 8;
    int s = rest / 64;
    int c = w * 16 + (lane & 15);
    int k = s * 256 + kt * 32 + (lane >> 4) * 8 + j;
    float v = Wproj[c * DD + k];
    __bf16 hi = (__bf16)v;
    __bf16 lo = (__bf16)(v - (float)hi);
    size_t base = (size_t)(((s * 8 + w) * 8 + kt) * 2) * 512 + lane * 8 + j;
    out[base] = hi;
    out[base + 512] = lo;
}

// E[c][j] = b_ih[j] + (j<1024 ? b_hh[j] : 0) + sum_k embed[c][k]*W_ih[j][k]; row 128 = biases only
__global__ void k_build_E(const float* __restrict__ embed, const float* __restrict__ WihT,
                          const float* __restrict__ b_ih, const float* __restrict__ b_hh,
                          float* __restrict__ E) {
    __shared__ float emb[16][DD];
    const int t = threadIdx.x;
    const int j = blockIdx.x * 256 + t;
    const int c0 = blockIdx.y * 16;
    for (int i = 0; i < 16; i++) {
        int c = c0 + i;
        for (int k = t; k < DD; k += 256)
            emb[i][k] = (c < CC) ? embed[c * DD + k] : 0.0f;
    }
    __syncthreads();
    float acc[16];
#pragma unroll
    for (int i = 0; i < 16; i++) acc[i] = 0.0f;
    for (int k = 0; k < DD; k++) {
        float wv = WihT[k * G3 + j];
#pragma unroll
        for (int i = 0; i < 16; i++) acc[i] = fmaf(emb[i][k], wv, acc[i]);
    }
    float bj = b_ih[j] + (j < 1024 ? b_hh[j] : 0.0f);
    for (int i = 0; i < 16; i++) {
        int c = c0 + i;
        if (c <= CC) E[(size_t)c * G3 + j] = acc[i] + bj;
    }
}

// ---------------- main persistent GRU kernel ----------------

__device__ __forceinline__ float fast_sigmoid(float x) {
    return __builtin_amdgcn_rcpf(1.0f + __expf(-x));
}
__device__ __forceinline__ float fast_tanh(float x) {
    x = fminf(10.0f, fmaxf(-10.0f, x));
    float e = __expf(2.0f * x);
    return (e - 1.0f) * __builtin_amdgcn_rcpf(e + 1.0f);
}

// COLUMN-SPLIT pair design: grid=256, blocks (pair, s) with s in {0,1}.
// Both blocks of a pair own the SAME 16 batch rows; block s computes gh columns
// for d in [s*256, s*256+256) of each gate (half the W_hh stream = 1.57 MB/step)
// and the k-half partial logits. Per step the pair exchanges h-halves (16 KB)
// and partial logits (8 KB) via agent-scope RELAXED atomics (MALL-coherent,
// L2-bypassing) + a flag handshake.
// CRITICAL (R3 lesson): the consumer spin must be RELAXED, not ACQUIRE —
// agent-scope acquire emits buffer_inv which wipes the XCD L2 (weights!)
// every step. Producer flag store keeps RELEASE: its buffer_wbl2 only writes
// back dirty lines (weights are clean) and orders the data stores.
// REQUIRES all 256 blocks co-resident: LDS > 80 KB forces 1 block/CU, grid == #CUs.
__global__ __launch_bounds__(512, 2) void k_gru(
    const float* __restrict__ feat, const __bf16* __restrict__ Whf,
    const __bf16* __restrict__ Wpf, const float* __restrict__ b_proj,
    const float* __restrict__ b_hh, const float* __restrict__ Ep,
    unsigned int* xh, float* xl, int* flags,
    float* __restrict__ out) {
    __shared__ __align__(16) __bf16 h_hi[16][520];  // 16.25 KB, +8 col pad
    __shared__ __align__(16) __bf16 h_lo[16][520];  // 16.25 KB
    __shared__ float plg[16][CC];                   // 8 KB logits (partial -> full)
    __shared__ float lgbuf[16][64][10];             // 40 KB output burst buffer (own 64 cols)
    __shared__ float bpj[CC];
    __shared__ int tok_s[16];

    float* out_logits = out;                      // [B][C][T]
    float* out_tok = out + (size_t)BB * CC * TT;  // [B][T] as float

    const int t = threadIdx.x;   // 0..511
    const int w = t >> 6;        // wave 0..7
    const int lane = t & 63;
    const int col = lane & 15;
    const int quad = lane >> 4;
    const int bq = quad * 4;

    // swizzle: XCDs 0-3 host s=0 halves, 4-7 host s=1 -> per-XCD L2 weight
    // resident set is one half (~1.6 MB) (perf heuristic only)
    const int bid = blockIdx.x;
    const int grp = bid & 7;
    const int s = grp >> 2;
    const int pair = (bid >> 3) * 4 + (grp & 3);  // 0..127
    const int row0 = pair * 16;
    const int fl_self = pair * 2 + s;

    // ---- init: full h0 into LDS; own-half h0 into registers
    for (int i = 0; i < 16; i++) {
        float v = feat[(size_t)(row0 + i) * DD + t];
        __bf16 hi = (__bf16)v;
        h_hi[i][t] = hi;
        h_lo[i][t] = (__bf16)(v - (float)hi);
    }
    float ho[2][4];
#pragma unroll
    for (int tl = 0; tl < 2; tl++) {
        const int d = s * 256 + w * 32 + tl * 16 + col;
#pragma unroll
        for (int rg = 0; rg < 4; rg++)
            ho[tl][rg] = feat[(size_t)(row0 + bq + rg) * DD + d];
    }
    if (t < CC) bpj[t] = b_proj[t];
    if (t < 16) tok_s[t] = CC;  // start token -> E row 128 (x0 = 0)

    float bhn_t[2];
#pragma unroll
    for (int tl = 0; tl < 2; tl++)
        bhn_t[tl] = b_hh[1024 + s * 256 + w * 32 + tl * 16 + col];

    const __bf16* wseq = Whf + (size_t)(s * 8 + w) * 98304;  // 16kt*6tile*2part*512
    const __bf16* wpseq = Wpf + (size_t)(s * 8 + w) * 8192;  // 8kt*2part*512
    __syncthreads();

    for (int step = 0; step < TT; step++) {
        const int sl = step & 7;
        const int par = step & 1;
        unsigned int* xh_self = xh + ((size_t)(pair * 2 + par) * 2 + s) * 4096;
        unsigned int* xh_part = xh + ((size_t)(pair * 2 + par) * 2 + (1 - s)) * 4096;
        float* xl_self = xl + ((size_t)(pair * 2 + par) * 2 + s) * 2048;
        float* xl_part = xl + ((size_t)(pair * 2 + par) * 2 + (1 - s)) * 2048;

        // ---- P1: own-half gh = h @ W_hh^T, split-bf16 MFMA, 6 tiles
        f32x4 acc[6];
#pragma unroll
        for (int i = 0; i < 6; i++) acc[i] = (f32x4)(0.0f);
        for (int kt = 0; kt < 16; kt++) {
            bf16x8 ahi = *(const bf16x8*)&h_hi[col][kt * 32 + quad * 8];
            bf16x8 alo = *(const bf16x8*)&h_lo[col][kt * 32 + quad * 8];
            const __bf16* wk = wseq + kt * 6144;
#pragma unroll
            for (int tile = 0; tile < 6; tile++) {
                bf16x8 bhi = *(const bf16x8*)(wk + tile * 1024 + lane * 8);
                bf16x8 blo = *(const bf16x8*)(wk + tile * 1024 + 512 + lane * 8);
                acc[tile] = __builtin_amdgcn_mfma_f32_16x16x32_bf16(ahi, bhi, acc[tile], 0, 0, 0);
                acc[tile] = __builtin_amdgcn_mfma_f32_16x16x32_bf16(alo, bhi, acc[tile], 0, 0, 0);
                acc[tile] = __builtin_amdgcn_mfma_f32_16x16x32_bf16(ahi, blo, acc[tile], 0, 0, 0);
            }
        }
        __syncthreads();  // all waves done reading h

        // ---- P2: gates for own 256 d; write h_new to LDS + exchange buffer
        {
            int tk[4];
#pragma unroll
            for (int rg = 0; rg < 4; rg++) tk[rg] = tok_s[bq + rg];
#pragma unroll
            for (int tl = 0; tl < 2; tl++) {
                const int d = s * 256 + w * 32 + tl * 16 + col;
                const int dl = d - s * 256;
#pragma unroll
                for (int rg = 0; rg < 4; rg++) {
                    const int b = bq + rg;
                    const float* Er = Ep + (size_t)tk[rg] * G3 + d;
                    float rr = fast_sigmoid(acc[tl][rg] + Er[0]);
                    float zz = fast_sigmoid(acc[2 + tl][rg] + Er[512]);
                    float nn = fast_tanh(Er[1024] + rr * (acc[4 + tl][rg] + bhn_t[tl]));
                    float hv = (1.0f - zz) * nn + zz * ho[tl][rg];
                    ho[tl][rg] = hv;
                    __bf16 hi = (__bf16)hv;
                    __bf16 lo = (__bf16)(hv - (float)hi);
                    h_hi[b][d] = hi;
                    h_lo[b][d] = lo;
                    unsigned int val = ((unsigned int)__builtin_bit_cast(unsigned short, hi) << 16) |
                                       (unsigned int)__builtin_bit_cast(unsigned short, lo);
                    __hip_atomic_store(&xh_self[b * 256 + dl], val, __ATOMIC_RELAXED,
                                       __HIP_MEMORY_SCOPE_AGENT);
                }
            }
        }
        __syncthreads();  // own-half h_new in LDS for P3a

        // ---- P3a: k-half partial logits; wave w -> cols [16w,16w+16)
        {
            f32x4 accp = (f32x4)(0.0f);
            for (int ktl = 0; ktl < 8; ktl++) {
                const int kt = s * 8 + ktl;
                bf16x8 ahi = *(const bf16x8*)&h_hi[col][kt * 32 + quad * 8];
                bf16x8 alo = *(const bf16x8*)&h_lo[col][kt * 32 + quad * 8];
                const __bf16* pk = wpseq + ktl * 1024;
                bf16x8 bhi = *(const bf16x8*)(pk + lane * 8);
                bf16x8 blo = *(const bf16x8*)(pk + 512 + lane * 8);
                accp = __builtin_amdgcn_mfma_f32_16x16x32_bf16(ahi, bhi, accp, 0, 0, 0);
                accp = __builtin_amdgcn_mfma_f32_16x16x32_bf16(alo, bhi, accp, 0, 0, 0);
                accp = __builtin_amdgcn_mfma_f32_16x16x32_bf16(ahi, blo, accp, 0, 0, 0);
            }
            const int c = w * 16 + col;
#pragma unroll
            for (int rg = 0; rg < 4; rg++) {
                plg[bq + rg][c] = accp[rg];
                __hip_atomic_store(&xl_self[(bq + rg) * CC + c], accp[rg], __ATOMIC_RELAXED,
                                   __HIP_MEMORY_SCOPE_AGENT);
            }
        }
        __syncthreads();  // all exchange stores drained (barrier implies vmcnt(0))

        // ---- handshake: publish flag (RELEASE: wbl2 harmless, orders stores),
        //      spin RELAXED (NO buffer_inv -> weights stay L2-resident)
        if (t == 0) {
            __hip_atomic_store(&flags[fl_self], step + 1, __ATOMIC_RELEASE,
                               __HIP_MEMORY_SCOPE_AGENT);
            while (__hip_atomic_load(&flags[fl_self ^ 1], __ATOMIC_RELAXED,
                                     __HIP_MEMORY_SCOPE_AGENT) < step + 1)
                __builtin_amdgcn_s_sleep(1);
        }
        __syncthreads();

        // ---- merge: partner h-half -> LDS; sum partials -> full logits
        for (int i = 0; i < 8; i++) {
            const int idx = t + i * 512;  // 4096
            const int b = idx >> 8, dl = idx & 255;
            unsigned int v = __hip_atomic_load(&xh_part[idx], __ATOMIC_RELAXED,
                                               __HIP_MEMORY_SCOPE_AGENT);
            h_hi[b][(1 - s) * 256 + dl] = __builtin_bit_cast(__bf16, (unsigned short)(v >> 16));
            h_lo[b][(1 - s) * 256 + dl] = __builtin_bit_cast(__bf16, (unsigned short)(v & 0xffff));
        }
        for (int i = 0; i < 4; i++) {
            const int idx = t + i * 512;  // 2048
            const int b = idx >> 7, c = idx & (CC - 1);
            float oth = __hip_atomic_load(&xl_part[idx], __ATOMIC_RELAXED,
                                          __HIP_MEMORY_SCOPE_AGENT);
            float own = plg[b][c];
            float p0 = (s == 0) ? own : oth;
            float p1 = (s == 0) ? oth : own;
            float lg = (p0 + p1) + bpj[c];  // identical bits in both blocks
            plg[b][c] = lg;
            if ((c >> 6) == s) lgbuf[b][c & 63][sl] = lg;
        }
        __syncthreads();  // full logits + partner h visible

        // ---- P3b: argmax; wave w handles rows 2w, 2w+1
        {
#pragma unroll
            for (int pass = 0; pass < 2; pass++) {
                const int r = w * 2 + pass;
                float v0 = plg[r][lane];
                float v1 = plg[r][lane + 64];
                float bv; int bi;
                if (v0 >= v1) { bv = v0; bi = lane; } else { bv = v1; bi = lane + 64; }
#pragma unroll
                for (int off = 32; off > 0; off >>= 1) {
                    float ov = __shfl_down(bv, off, 64);
                    int oi = __shfl_down(bi, off, 64);
                    if (ov > bv || (ov == bv && oi < bi)) { bv = ov; bi = oi; }
                }
                if (lane == 0) {
                    tok_s[r] = bi;
                    if (s == 0)
                        __builtin_nontemporal_store(
                            (float)bi, &out_tok[(size_t)(row0 + r) * TT + step]);
                }
            }
        }
        __syncthreads();  // tok_s + lgbuf stable

        // ---- flush own 64-col logit slice every 8 steps (nontemporal)
        if ((step & 7) == 7 || step == TT - 1) {
            const int t0 = step & ~7;
            const int cnt = step - t0 + 1;
#pragma unroll
            for (int p = 0; p < 2; p++) {
                const int pr = t + p * 512;  // 0..1023
                const int b = pr >> 6, c64 = pr & 63;
                float* dst = out_logits + ((size_t)(row0 + b) * CC + (s * 64 + c64)) * TT + t0;
                const float* src = &lgbuf[b][c64][0];
                for (int q = 0; q < cnt; q++) __builtin_nontemporal_store(src[q], &dst[q]);
            }
        }
    }
}

// ---------------- launcher ----------------

extern "C" void kernel_launch(void* const* d_in, const int* in_sizes, int n_in,
                              void* d_out, int out_size, void* d_ws, size_t ws_size,
                              hipStream_t stream) {
    const float* feat   = (const float*)d_in[0];
    const float* W_ih   = (const float*)d_in[1];
    const float* W_hh   = (const float*)d_in[2];
    const float* b_ih   = (const float*)d_in[3];
    const float* b_hh   = (const float*)d_in[4];
    const float* W_proj = (const float*)d_in[5];
    const float* b_proj = (const float*)d_in[6];
    const float* embed  = (const float*)d_in[7];
    float* out = (float*)d_out;

    float* ws = (float*)d_ws;
    float*        WihT  = ws;                              // 786432 floats
    float*        E     = ws + 786432;                     // 198144 floats
    __bf16*       Whf   = (__bf16*)(ws + 984576);          // 1572864 bf16 = 786432 slots
    __bf16*       Wpf   = (__bf16*)(ws + 1771008);         // 131072 bf16 = 65536 slots
    unsigned int* xh    = (unsigned int*)(ws + 1836544);   // 2097152 uints
    float*        xl    = ws + 3933696;                    // 1048576 floats
    int*          flags = (int*)(ws + 4982272);            // 256 ints
    // total ~19.9 MB

    hipMemsetAsync(flags, 0, 256 * sizeof(int), stream);
    hipLaunchKernelGGL(k_transpose_wih, dim3(3072), dim3(256), 0, stream, W_ih, WihT);
    hipLaunchKernelGGL(k_pack_wp_frag, dim3(256), dim3(256), 0, stream, W_proj, Wpf);
    hipLaunchKernelGGL(k_pack_whh_frag, dim3(3072), dim3(256), 0, stream, W_hh, Whf);
    hipLaunchKernelGGL(k_build_E, dim3(6, 9), dim3(256), 0, stream, embed, WihT, b_ih, b_hh, E);
    hipLaunchKernelGGL(k_gru, dim3(256), dim3(512), 0, stream,
                       feat, Whf, Wpf, b_proj, b_hh, E, xh, xl, flags, out);
}

// Round 5
// 19082.584 us; speedup vs baseline: 1.0879x; 1.0680x over previous
//
#include <hip/hip_runtime.h>
#include <math.h>

#define BB 2048
#define DD 512
#define CC 128
#define TT 151
#define G3 1536  // 3*D

typedef __bf16 bf16x8 __attribute__((ext_vector_type(8)));
typedef float f32x4 __attribute__((ext_vector_type(4)));

// ---------------- precompute kernels ----------------

// WihT[k*G3 + j] = Wih[j*DD + k]  (for E build)
__global__ void k_transpose_wih(const float* __restrict__ Wih, float* __restrict__ WihT) {
    int idx = blockIdx.x * 256 + threadIdx.x;
    if (idx < G3 * DD) {
        int j = idx / DD, k = idx - j * DD;
        WihT[k * G3 + j] = Wih[idx];
    }
}

// W_hh split-bf16 B-fragments, COLUMN-SPLIT layout across block pairs.
// [s 0..1][w 0..7][kt 0..15][tile 0..5 (g*2+tl)][part hi/lo][lane 0..63][j 0..7]
//   jcol = g*512 + s*256 + w*32 + tl*16 + (lane&15),  k = kt*32 + (lane>>4)*8 + j
__global__ void k_pack_whh_frag(const float* __restrict__ Whh, __bf16* __restrict__ out) {
    int idx = blockIdx.x * 256 + threadIdx.x;  // 786432
    if (idx >= 786432) return;
    int j8 = idx & 7;
    int lane = (idx >> 3) & 63;
    int rest = idx >> 9;          // 0..1535
    int tile = rest % 6;
    int kt = (rest / 6) % 16;
    int w = (rest / 96) % 8;
    int s = rest / 768;
    int g = tile >> 1, tl = tile & 1;
    int jcol = g * 512 + s * 256 + w * 32 + tl * 16 + (lane & 15);
    int k = kt * 32 + (lane >> 4) * 8 + j8;
    float v = Whh[jcol * DD + k];
    __bf16 hi = (__bf16)v;
    __bf16 lo = (__bf16)(v - (float)hi);
    size_t base = (size_t)((((s * 8 + w) * 16 + kt) * 6 + tile) * 2) * 512 + lane * 8 + j8;
    out[base] = hi;
    out[base + 512] = lo;
}

// W_proj split-bf16 B-fragments, K-HALF split: [s][w][kt 0..7][part][lane][8]
//   c = w*16 + (lane&15),  k = s*256 + kt*32 + (lane>>4)*8 + j
__global__ void k_pack_wp_frag(const float* __restrict__ Wproj, __bf16* __restrict__ out) {
    int idx = blockIdx.x * 256 + threadIdx.x;  // 65536
    if (idx >= 65536) return;
    int j = idx & 7;
    int lane = (idx >> 3) & 63;
    int rest = idx >> 9;          // 0..127
    int kt = rest % 8;
    int w = (rest / 8) % 8;
    int s = rest / 64;
    int c = w * 16 + (lane & 15);
    int k = s * 256 + kt * 32 + (lane >> 4) * 8 + j;
    float v = Wproj[c * DD + k];
    __bf16 hi = (__bf16)v;
    __bf16 lo = (__bf16)(v - (float)hi);
    size_t base = (size_t)(((s * 8 + w) * 8 + kt) * 2) * 512 + lane * 8 + j;
    out[base] = hi;
    out[base + 512] = lo;
}

// E[c][j] = b_ih[j] + (j<1024 ? b_hh[j] : 0) + sum_k embed[c][k]*W_ih[j][k]; row 128 = biases only
__global__ void k_build_E(const float* __restrict__ embed, const float* __restrict__ WihT,
                          const float* __restrict__ b_ih, const float* __restrict__ b_hh,
                          float* __restrict__ E) {
    __shared__ float emb[16][DD];
    const int t = threadIdx.x;
    const int j = blockIdx.x * 256 + t;
    const int c0 = blockIdx.y * 16;
    for (int i = 0; i < 16; i++) {
        int c = c0 + i;
        for (int k = t; k < DD; k += 256)
            emb[i][k] = (c < CC) ? embed[c * DD + k] : 0.0f;
    }
    __syncthreads();
    float acc[16];
#pragma unroll
    for (int i = 0; i < 16; i++) acc[i] = 0.0f;
    for (int k = 0; k < DD; k++) {
        float wv = WihT[k * G3 + j];
#pragma unroll
        for (int i = 0; i < 16; i++) acc[i] = fmaf(emb[i][k], wv, acc[i]);
    }
    float bj = b_ih[j] + (j < 1024 ? b_hh[j] : 0.0f);
    for (int i = 0; i < 16; i++) {
        int c = c0 + i;
        if (c <= CC) E[(size_t)c * G3 + j] = acc[i] + bj;
    }
}

// ---------------- main persistent GRU kernel ----------------

__device__ __forceinline__ float fast_sigmoid(float x) {
    return __builtin_amdgcn_rcpf(1.0f + __expf(-x));
}
__device__ __forceinline__ float fast_tanh(float x) {
    x = fminf(10.0f, fmaxf(-10.0f, x));
    float e = __expf(2.0f * x);
    return (e - 1.0f) * __builtin_amdgcn_rcpf(e + 1.0f);
}

// COLUMN-SPLIT pair design: grid=256, blocks (pair, s) with s in {0,1}.
// Both blocks of a pair own the SAME 16 batch rows; block s computes gh columns
// for d in [s*256, s*256+256) of each gate (half the W_hh stream = 1.57 MB/step)
// and the k-half partial logits. Per step the pair exchanges h-halves (16 KB)
// and partial logits (8 KB) via agent-scope RELAXED atomics (UC/MALL-coherent).
// CRITICAL (R3/R4 lesson): NO release OR acquire anywhere in the step loop.
// R3 (acq+rel) == R4 (rel only) at FETCH 28 GB proved acquire's buffer_inv
// innocent; the release's buffer_wbl2 (per block per step) is the remaining
// maintenance op that wipes the XCD L2 holding the weights. Ordering without
// release: __syncthreads() drains vmcnt(0) (UC stores acked at MALL) and is a
// compiler barrier; the flag store (UC, issued after) can only land later.
// REQUIRES all 256 blocks co-resident: LDS > 80 KB forces 1 block/CU, grid == #CUs.
__global__ __launch_bounds__(512, 2) void k_gru(
    const float* __restrict__ feat, const __bf16* __restrict__ Whf,
    const __bf16* __restrict__ Wpf, const float* __restrict__ b_proj,
    const float* __restrict__ b_hh, const float* __restrict__ Ep,
    unsigned int* xh, float* xl, int* flags,
    float* __restrict__ out) {
    __shared__ __align__(16) __bf16 h_hi[16][520];  // 16.25 KB, +8 col pad
    __shared__ __align__(16) __bf16 h_lo[16][520];  // 16.25 KB
    __shared__ float plg[16][CC];                   // 8 KB logits (partial -> full)
    __shared__ float lgbuf[16][64][10];             // 40 KB output burst buffer (own 64 cols)
    __shared__ float bpj[CC];
    __shared__ int tok_s[16];

    float* out_logits = out;                      // [B][C][T]
    float* out_tok = out + (size_t)BB * CC * TT;  // [B][T] as float

    const int t = threadIdx.x;   // 0..511
    const int w = t >> 6;        // wave 0..7
    const int lane = t & 63;
    const int col = lane & 15;
    const int quad = lane >> 4;
    const int bq = quad * 4;

    // swizzle: XCDs 0-3 host s=0 halves, 4-7 host s=1 -> per-XCD L2 weight
    // resident set is one half (~1.6 MB) (perf heuristic only)
    const int bid = blockIdx.x;
    const int grp = bid & 7;
    const int s = grp >> 2;
    const int pair = (bid >> 3) * 4 + (grp & 3);  // 0..127
    const int row0 = pair * 16;
    const int fl_self = pair * 2 + s;

    // ---- init: full h0 into LDS; own-half h0 into registers
    for (int i = 0; i < 16; i++) {
        float v = feat[(size_t)(row0 + i) * DD + t];
        __bf16 hi = (__bf16)v;
        h_hi[i][t] = hi;
        h_lo[i][t] = (__bf16)(v - (float)hi);
    }
    float ho[2][4];
#pragma unroll
    for (int tl = 0; tl < 2; tl++) {
        const int d = s * 256 + w * 32 + tl * 16 + col;
#pragma unroll
        for (int rg = 0; rg < 4; rg++)
            ho[tl][rg] = feat[(size_t)(row0 + bq + rg) * DD + d];
    }
    if (t < CC) bpj[t] = b_proj[t];
    if (t < 16) tok_s[t] = CC;  // start token -> E row 128 (x0 = 0)

    float bhn_t[2];
#pragma unroll
    for (int tl = 0; tl < 2; tl++)
        bhn_t[tl] = b_hh[1024 + s * 256 + w * 32 + tl * 16 + col];

    const __bf16* wseq = Whf + (size_t)(s * 8 + w) * 98304;  // 16kt*6tile*2part*512
    const __bf16* wpseq = Wpf + (size_t)(s * 8 + w) * 8192;  // 8kt*2part*512
    __syncthreads();

    for (int step = 0; step < TT; step++) {
        const int sl = step & 7;
        const int par = step & 1;
        unsigned int* xh_self = xh + ((size_t)(pair * 2 + par) * 2 + s) * 4096;
        unsigned int* xh_part = xh + ((size_t)(pair * 2 + par) * 2 + (1 - s)) * 4096;
        float* xl_self = xl + ((size_t)(pair * 2 + par) * 2 + s) * 2048;
        float* xl_part = xl + ((size_t)(pair * 2 + par) * 2 + (1 - s)) * 2048;

        // ---- P1: own-half gh = h @ W_hh^T, split-bf16 MFMA, 6 tiles
        f32x4 acc[6];
#pragma unroll
        for (int i = 0; i < 6; i++) acc[i] = (f32x4)(0.0f);
        for (int kt = 0; kt < 16; kt++) {
            bf16x8 ahi = *(const bf16x8*)&h_hi[col][kt * 32 + quad * 8];
            bf16x8 alo = *(const bf16x8*)&h_lo[col][kt * 32 + quad * 8];
            const __bf16* wk = wseq + kt * 6144;
#pragma unroll
            for (int tile = 0; tile < 6; tile++) {
                bf16x8 bhi = *(const bf16x8*)(wk + tile * 1024 + lane * 8);
                bf16x8 blo = *(const bf16x8*)(wk + tile * 1024 + 512 + lane * 8);
                acc[tile] = __builtin_amdgcn_mfma_f32_16x16x32_bf16(ahi, bhi, acc[tile], 0, 0, 0);
                acc[tile] = __builtin_amdgcn_mfma_f32_16x16x32_bf16(alo, bhi, acc[tile], 0, 0, 0);
                acc[tile] = __builtin_amdgcn_mfma_f32_16x16x32_bf16(ahi, blo, acc[tile], 0, 0, 0);
            }
        }
        __syncthreads();  // all waves done reading h

        // ---- P2: gates for own 256 d; write h_new to LDS + exchange buffer
        {
            int tk[4];
#pragma unroll
            for (int rg = 0; rg < 4; rg++) tk[rg] = tok_s[bq + rg];
#pragma unroll
            for (int tl = 0; tl < 2; tl++) {
                const int d = s * 256 + w * 32 + tl * 16 + col;
                const int dl = d - s * 256;
#pragma unroll
                for (int rg = 0; rg < 4; rg++) {
                    const int b = bq + rg;
                    const float* Er = Ep + (size_t)tk[rg] * G3 + d;
                    float rr = fast_sigmoid(acc[tl][rg] + Er[0]);
                    float zz = fast_sigmoid(acc[2 + tl][rg] + Er[512]);
                    float nn = fast_tanh(Er[1024] + rr * (acc[4 + tl][rg] + bhn_t[tl]));
                    float hv = (1.0f - zz) * nn + zz * ho[tl][rg];
                    ho[tl][rg] = hv;
                    __bf16 hi = (__bf16)hv;
                    __bf16 lo = (__bf16)(hv - (float)hi);
                    h_hi[b][d] = hi;
                    h_lo[b][d] = lo;
                    unsigned int val = ((unsigned int)__builtin_bit_cast(unsigned short, hi) << 16) |
                                       (unsigned int)__builtin_bit_cast(unsigned short, lo);
                    __hip_atomic_store(&xh_self[b * 256 + dl], val, __ATOMIC_RELAXED,
                                       __HIP_MEMORY_SCOPE_AGENT);
                }
            }
        }
        __syncthreads();  // own-half h_new in LDS for P3a

        // ---- P3a: k-half partial logits; wave w -> cols [16w,16w+16)
        {
            f32x4 accp = (f32x4)(0.0f);
            for (int ktl = 0; ktl < 8; ktl++) {
                const int kt = s * 8 + ktl;
                bf16x8 ahi = *(const bf16x8*)&h_hi[col][kt * 32 + quad * 8];
                bf16x8 alo = *(const bf16x8*)&h_lo[col][kt * 32 + quad * 8];
                const __bf16* pk = wpseq + ktl * 1024;
                bf16x8 bhi = *(const bf16x8*)(pk + lane * 8);
                bf16x8 blo = *(const bf16x8*)(pk + 512 + lane * 8);
                accp = __builtin_amdgcn_mfma_f32_16x16x32_bf16(ahi, bhi, accp, 0, 0, 0);
                accp = __builtin_amdgcn_mfma_f32_16x16x32_bf16(alo, bhi, accp, 0, 0, 0);
                accp = __builtin_amdgcn_mfma_f32_16x16x32_bf16(ahi, blo, accp, 0, 0, 0);
            }
            const int c = w * 16 + col;
#pragma unroll
            for (int rg = 0; rg < 4; rg++) {
                plg[bq + rg][c] = accp[rg];
                __hip_atomic_store(&xl_self[(bq + rg) * CC + c], accp[rg], __ATOMIC_RELAXED,
                                   __HIP_MEMORY_SCOPE_AGENT);
            }
        }
        __syncthreads();  // all exchange stores drained (barrier implies vmcnt(0))

        // ---- handshake: publish flag RELAXED (no wbl2! ordering via the
        //      vmcnt(0)-draining barrier above), spin RELAXED (no buffer_inv)
        if (t == 0) {
            __hip_atomic_store(&flags[fl_self], step + 1, __ATOMIC_RELAXED,
                               __HIP_MEMORY_SCOPE_AGENT);
            while (__hip_atomic_load(&flags[fl_self ^ 1], __ATOMIC_RELAXED,
                                     __HIP_MEMORY_SCOPE_AGENT) < step + 1)
                __builtin_amdgcn_s_sleep(1);
        }
        __syncthreads();

        // ---- merge: partner h-half -> LDS; sum partials -> full logits
        for (int i = 0; i < 8; i++) {
            const int idx = t + i * 512;  // 4096
            const int b = idx >> 8, dl = idx & 255;
            unsigned int v = __hip_atomic_load(&xh_part[idx], __ATOMIC_RELAXED,
                                               __HIP_MEMORY_SCOPE_AGENT);
            h_hi[b][(1 - s) * 256 + dl] = __builtin_bit_cast(__bf16, (unsigned short)(v >> 16));
            h_lo[b][(1 - s) * 256 + dl] = __builtin_bit_cast(__bf16, (unsigned short)(v & 0xffff));
        }
        for (int i = 0; i < 4; i++) {
            const int idx = t + i * 512;  // 2048
            const int b = idx >> 7, c = idx & (CC - 1);
            float oth = __hip_atomic_load(&xl_part[idx], __ATOMIC_RELAXED,
                                          __HIP_MEMORY_SCOPE_AGENT);
            float own = plg[b][c];
            float p0 = (s == 0) ? own : oth;
            float p1 = (s == 0) ? oth : own;
            float lg = (p0 + p1) + bpj[c];  // identical bits in both blocks
            plg[b][c] = lg;
            if ((c >> 6) == s) lgbuf[b][c & 63][sl] = lg;
        }
        __syncthreads();  // full logits + partner h visible

        // ---- P3b: argmax; wave w handles rows 2w, 2w+1
        {
#pragma unroll
            for (int pass = 0; pass < 2; pass++) {
                const int r = w * 2 + pass;
                float v0 = plg[r][lane];
                float v1 = plg[r][lane + 64];
                float bv; int bi;
                if (v0 >= v1) { bv = v0; bi = lane; } else { bv = v1; bi = lane + 64; }
#pragma unroll
                for (int off = 32; off > 0; off >>= 1) {
                    float ov = __shfl_down(bv, off, 64);
                    int oi = __shfl_down(bi, off, 64);
                    if (ov > bv || (ov == bv && oi < bi)) { bv = ov; bi = oi; }
                }
                if (lane == 0) {
                    tok_s[r] = bi;
                    if (s == 0)
                        __builtin_nontemporal_store(
                            (float)bi, &out_tok[(size_t)(row0 + r) * TT + step]);
                }
            }
        }
        __syncthreads();  // tok_s + lgbuf stable

        // ---- flush own 64-col logit slice every 8 steps (nontemporal)
        if ((step & 7) == 7 || step == TT - 1) {
            const int t0 = step & ~7;
            const int cnt = step - t0 + 1;
#pragma unroll
            for (int p = 0; p < 2; p++) {
                const int pr = t + p * 512;  // 0..1023
                const int b = pr >> 6, c64 = pr & 63;
                float* dst = out_logits + ((size_t)(row0 + b) * CC + (s * 64 + c64)) * TT + t0;
                const float* src = &lgbuf[b][c64][0];
                for (int q = 0; q < cnt; q++) __builtin_nontemporal_store(src[q], &dst[q]);
            }
        }
    }
}

// ---------------- launcher ----------------

extern "C" void kernel_launch(void* const* d_in, const int* in_sizes, int n_in,
                              void* d_out, int out_size, void* d_ws, size_t ws_size,
                              hipStream_t stream) {
    const float* feat   = (const float*)d_in[0];
    const float* W_ih   = (const float*)d_in[1];
    const float* W_hh   = (const float*)d_in[2];
    const float* b_ih   = (const float*)d_in[3];
    const float* b_hh   = (const float*)d_in[4];
    const float* W_proj = (const float*)d_in[5];
    const float* b_proj = (const float*)d_in[6];
    const float* embed  = (const float*)d_in[7];
    float* out = (float*)d_out;

    float* ws = (float*)d_ws;
    float*        WihT  = ws;                              // 786432 floats
    float*        E     = ws + 786432;                     // 198144 floats
    __bf16*       Whf   = (__bf16*)(ws + 984576);          // 1572864 bf16 = 786432 slots
    __bf16*       Wpf   = (__bf16*)(ws + 1771008);         // 131072 bf16 = 65536 slots
    unsigned int* xh    = (unsigned int*)(ws + 1836544);   // 2097152 uints
    float*        xl    = ws + 3933696;                    // 1048576 floats
    int*          flags = (int*)(ws + 4982272);            // 256 ints
    // total ~19.9 MB

    hipMemsetAsync(flags, 0, 256 * sizeof(int), stream);
    hipLaunchKernelGGL(k_transpose_wih, dim3(3072), dim3(256), 0, stream, W_ih, WihT);
    hipLaunchKernelGGL(k_pack_wp_frag, dim3(256), dim3(256), 0, stream, W_proj, Wpf);
    hipLaunchKernelGGL(k_pack_whh_frag, dim3(3072), dim3(256), 0, stream, W_hh, Whf);
    hipLaunchKernelGGL(k_build_E, dim3(6, 9), dim3(256), 0, stream, embed, WihT, b_ih, b_hh, E);
    hipLaunchKernelGGL(k_gru, dim3(256), dim3(512), 0, stream,
                       feat, Whf, Wpf, b_proj, b_hh, E, xh, xl, flags, out);
}

// Round 8
// 7008.001 us; speedup vs baseline: 2.9622x; 2.7230x over previous
//
#include <hip/hip_runtime.h>
#include <math.h>

#define BB 2048
#define DD 512
#define CC 128
#define TT 151
#define G3 1536  // 3*D

typedef __bf16 bf16x8 __attribute__((ext_vector_type(8)));
typedef float f32x4 __attribute__((ext_vector_type(4)));

// ---------------- precompute kernels ----------------

// WihT[k*G3 + j] = Wih[j*DD + k]  (for E build)
__global__ void k_transpose_wih(const float* __restrict__ Wih, float* __restrict__ WihT) {
    int idx = blockIdx.x * 256 + threadIdx.x;
    if (idx < G3 * DD) {
        int j = idx / DD, k = idx - j * DD;
        WihT[k * G3 + j] = Wih[idx];
    }
}

// Pack W_proj into split-bf16 MFMA B-fragments, one 16-col tile per wave.
// out[w*16384 + kt*1024 + part*512 + lane*8 + j]:
//   c = w*16 + (lane&15), k = kt*32 + (lane>>4)*8 + j, part 0=hi 1=lo
__global__ void k_pack_wp_frag(const float* __restrict__ Wproj, __bf16* __restrict__ out) {
    int idx = blockIdx.x * 256 + threadIdx.x;  // 131072
    if (idx >= 131072) return;
    int j = idx & 7;
    int lane = (idx >> 3) & 63;
    int part = (idx >> 9) & 1;
    int kt = (idx >> 10) & 15;
    int w = idx >> 14;
    int c = w * 16 + (lane & 15);
    int k = kt * 32 + (lane >> 4) * 8 + j;
    float v = Wproj[c * DD + k];
    __bf16 hi = (__bf16)v;
    out[idx] = part ? (__bf16)(v - (float)hi) : hi;
}

// Pack W_hh into split-bf16 B-fragments in per-wave streaming order.
// Layout: [w 0..7][kt 0..15][tile 0..11][part hi/lo][lane 0..63][j 0..7]  (bf16)
// tile: 0..3 -> r-gate, 4..7 -> z, 8..11 -> n.  For wave w, tile t (tl=t&3):
//   jcol = (t>>2)*512 + w*64 + tl*16 + (lane&15),  k = kt*32 + (lane>>4)*8 + j
__global__ void k_pack_whh_frag(const float* __restrict__ Whh, __bf16* __restrict__ out) {
    int idx = blockIdx.x * 256 + threadIdx.x;  // 786432
    if (idx >= 786432) return;
    int j8 = idx & 7;
    int lane = (idx >> 3) & 63;
    int rest = idx >> 9;          // tile + 12*(kt + 16*w)
    int tile = rest % 12;
    int kt = (rest / 12) % 16;
    int w = rest / (12 * 16);
    int g = tile >> 2, tl = tile & 3;
    int colc = lane & 15, quad = lane >> 4;
    int jcol = g * 512 + w * 64 + tl * 16 + colc;
    int k = kt * 32 + quad * 8 + j8;
    float v = Whh[jcol * DD + k];
    __bf16 hi = (__bf16)v;
    __bf16 lo = (__bf16)(v - (float)hi);
    size_t base = ((((size_t)w * 16 + kt) * 12 + tile) * 2) * 512 + lane * 8 + j8;
    out[base] = hi;
    out[base + 512] = lo;
}

// E[c][j] = b_ih[j] + (j<1024 ? b_hh[j] : 0) + sum_k embed[c][k]*W_ih[j][k]; row 128 = biases only
__global__ void k_build_E(const float* __restrict__ embed, const float* __restrict__ WihT,
                          const float* __restrict__ b_ih, const float* __restrict__ b_hh,
                          float* __restrict__ E) {
    __shared__ float emb[16][DD];
    const int t = threadIdx.x;
    const int j = blockIdx.x * 256 + t;
    const int c0 = blockIdx.y * 16;
    for (int i = 0; i < 16; i++) {
        int c = c0 + i;
        for (int k = t; k < DD; k += 256)
            emb[i][k] = (c < CC) ? embed[c * DD + k] : 0.0f;
    }
    __syncthreads();
    float acc[16];
#pragma unroll
    for (int i = 0; i < 16; i++) acc[i] = 0.0f;
    for (int k = 0; k < DD; k++) {
        float wv = WihT[k * G3 + j];
#pragma unroll
        for (int i = 0; i < 16; i++) acc[i] = fmaf(emb[i][k], wv, acc[i]);
    }
    float bj = b_ih[j] + (j < 1024 ? b_hh[j] : 0.0f);
    for (int i = 0; i < 16; i++) {
        int c = c0 + i;
        if (c <= CC) E[(size_t)c * G3 + j] = acc[i] + bj;
    }
}

// ---------------- main persistent GRU kernel ----------------

__device__ __forceinline__ float fast_sigmoid(float x) {
    return __builtin_amdgcn_rcpf(1.0f + __expf(-x));
}
__device__ __forceinline__ float fast_tanh(float x) {
    x = fminf(10.0f, fmaxf(-10.0f, x));
    float e = __expf(2.0f * x);
    return (e - 1.0f) * __builtin_amdgcn_rcpf(e + 1.0f);
}

// R1-proven structure (16 rows/block, grid 128, split-bf16 weights) +
// SOFTWARE-PIPELINED weight stream. R1 diagnosis: ~2 outstanding loads/wave
// -> 226 cyc/load = pure L2-latency serialization (87 GB/s/CU). Fix: 2-deep
// register double-buffer at half-kt (6-tile) granularity -> 24 loads in
// flight/wave. Weights are step-invariant, so the mod-32/mod-16 chunk
// wraparound auto-prefetches next step's first chunks across the barriers.
// MFMA order is BIT-IDENTICAL to R1 (only load scheduling changed).
// LOADW chunk c: kt=c>>1, tiles (c&1)*6 .. +5 of that kt.
#define LOADW(buf, c)                                                               \
    do {                                                                            \
        const int cc_ = (c) & 31;                                                   \
        const __bf16* wq_ = wseq + (cc_ >> 1) * 12288 + (cc_ & 1) * 6144 + lane * 8;\
        _Pragma("unroll")                                                           \
        for (int i_ = 0; i_ < 6; i_++) {                                            \
            buf##hi[i_] = *(const bf16x8*)(wq_ + i_ * 1024);                        \
            buf##lo[i_] = *(const bf16x8*)(wq_ + i_ * 1024 + 512);                  \
        }                                                                           \
    } while (0)

#define LOADP(buf, c)                                                               \
    do {                                                                            \
        const int cc_ = (c) & 15;                                                   \
        const __bf16* pq_ = wpseq + cc_ * 1024 + lane * 8;                          \
        buf##hi = *(const bf16x8*)(pq_);                                            \
        buf##lo = *(const bf16x8*)(pq_ + 512);                                      \
    } while (0)

__global__ __launch_bounds__(512, 2) void k_gru(
    const float* __restrict__ feat, const __bf16* __restrict__ Whf,
    const __bf16* __restrict__ Wpf, const float* __restrict__ b_proj,
    const float* __restrict__ b_hh, const float* __restrict__ Ep,
    float* __restrict__ out) {
    __shared__ __align__(16) __bf16 h_hi[16][520];  // 16.25 KB, +8 col pad
    __shared__ __align__(16) __bf16 h_lo[16][520];  // 16.25 KB
    __shared__ float lgbuf[16][CC][9];              // 72 KB logit burst buffer (+1 pad)
    __shared__ int tok_s[16];

    float* out_logits = out;                      // [B][C][T]
    float* out_tok = out + (size_t)BB * CC * TT;  // [B][T] as float

    const int t = threadIdx.x;   // 0..511
    const int w = t >> 6;        // wave 0..7: owns gh cols [64w,64w+64) per gate
    const int lane = t & 63;
    const int row0 = blockIdx.x * 16;
    const int col = lane & 15;   // MFMA A-row / D-col index
    const int quad = lane >> 4;
    const int bq = quad * 4;     // D-frag base row

    // ---- init: h0 = feat -> registers (h_old) + split-bf16 LDS
    float ho[4][4];  // [tile][rg] : h_old for (b=bq+rg, d=w*64+tile*16+col)
#pragma unroll
    for (int tile = 0; tile < 4; tile++) {
        const int d = w * 64 + tile * 16 + col;
#pragma unroll
        for (int rg = 0; rg < 4; rg++) {
            const int b = bq + rg;
            float v = feat[(size_t)(row0 + b) * DD + d];
            ho[tile][rg] = v;
            __bf16 hi = (__bf16)v;
            h_hi[b][d] = hi;
            h_lo[b][d] = (__bf16)(v - (float)hi);
        }
    }
    if (t < 16) tok_s[t] = CC;  // start token -> E row 128 (x0 = 0)

    // per-lane constants
    const float bp = b_proj[w * 16 + col];
    float bhn_t[4];
#pragma unroll
    for (int tile = 0; tile < 4; tile++)
        bhn_t[tile] = b_hh[1024 + w * 64 + tile * 16 + col];

    const __bf16* wseq = Whf + (size_t)w * 196608;  // per-wave W_hh stream
    const __bf16* wpseq = Wpf + (size_t)w * 16384;  // per-wave W_proj stream
    __syncthreads();

    // ---- persistent weight-stream pipeline buffers (live across steps)
    bf16x8 Phi[6], Plo[6], Qhi[6], Qlo[6];  // W_hh chunks (96 VGPR)
    bf16x8 Rhi, Rlo, Shi, Slo;              // W_proj kt buffers (16 VGPR)
    LOADW(P, 0);
    LOADW(Q, 1);
    LOADP(R, 0);
    LOADP(S, 1);

    for (int step = 0; step < TT; step++) {
        const int sl = step & 7;

        // ---- P1: gh = h @ W_hh^T via split-bf16 MFMA, 2-deep pipelined stream
        f32x4 acc[12];
#pragma unroll
        for (int i = 0; i < 12; i++) acc[i] = (f32x4)(0.0f);
        for (int kt = 0; kt < 16; kt++) {
            bf16x8 ahi = *(const bf16x8*)&h_hi[col][kt * 32 + quad * 8];
            bf16x8 alo = *(const bf16x8*)&h_lo[col][kt * 32 + quad * 8];
#pragma unroll
            for (int i = 0; i < 6; i++) {
                acc[i] = __builtin_amdgcn_mfma_f32_16x16x32_bf16(ahi, Phi[i], acc[i], 0, 0, 0);
                acc[i] = __builtin_amdgcn_mfma_f32_16x16x32_bf16(alo, Phi[i], acc[i], 0, 0, 0);
                acc[i] = __builtin_amdgcn_mfma_f32_16x16x32_bf16(ahi, Plo[i], acc[i], 0, 0, 0);
            }
            LOADW(P, 2 * kt + 2);  // kt=15 wraps to chunk 0: next step's prefetch
#pragma unroll
            for (int i = 0; i < 6; i++) {
                acc[6 + i] = __builtin_amdgcn_mfma_f32_16x16x32_bf16(ahi, Qhi[i], acc[6 + i], 0, 0, 0);
                acc[6 + i] = __builtin_amdgcn_mfma_f32_16x16x32_bf16(alo, Qhi[i], acc[6 + i], 0, 0, 0);
                acc[6 + i] = __builtin_amdgcn_mfma_f32_16x16x32_bf16(ahi, Qlo[i], acc[6 + i], 0, 0, 0);
            }
            LOADW(Q, 2 * kt + 3);  // kt=15 wraps to chunk 1
        }
        __syncthreads();  // all waves done reading h_hi/h_lo

        // ---- P2: gates in registers; D-frag (row=bq+rg, col=w*64+tile*16+col)
        {
            int tk[4];
#pragma unroll
            for (int rg = 0; rg < 4; rg++) tk[rg] = tok_s[bq + rg];
#pragma unroll
            for (int tile = 0; tile < 4; tile++) {
                const int d = w * 64 + tile * 16 + col;
#pragma unroll
                for (int rg = 0; rg < 4; rg++) {
                    const int b = bq + rg;
                    const float* Er = Ep + (size_t)tk[rg] * G3 + d;
                    float rr = fast_sigmoid(acc[tile][rg] + Er[0]);        // E has b_ih+b_hh(r)
                    float zz = fast_sigmoid(acc[4 + tile][rg] + Er[512]);  // E has b_ih+b_hh(z)
                    float nn = fast_tanh(Er[1024] + rr * (acc[8 + tile][rg] + bhn_t[tile]));
                    float hv = (1.0f - zz) * nn + zz * ho[tile][rg];
                    ho[tile][rg] = hv;
                    __bf16 hi = (__bf16)hv;
                    h_hi[b][d] = hi;
                    h_lo[b][d] = (__bf16)(hv - (float)hi);
                }
            }
        }
        __syncthreads();  // h_new visible

        // ---- P3a: logits via split-bf16 MFMA, pipelined; wave w -> cols [16w,16w+16)
        {
            f32x4 accp = (f32x4)(0.0f);
            for (int kt = 0; kt < 16; kt += 2) {
                {
                    bf16x8 ahi = *(const bf16x8*)&h_hi[col][kt * 32 + quad * 8];
                    bf16x8 alo = *(const bf16x8*)&h_lo[col][kt * 32 + quad * 8];
                    accp = __builtin_amdgcn_mfma_f32_16x16x32_bf16(ahi, Rhi, accp, 0, 0, 0);
                    accp = __builtin_amdgcn_mfma_f32_16x16x32_bf16(alo, Rhi, accp, 0, 0, 0);
                    accp = __builtin_amdgcn_mfma_f32_16x16x32_bf16(ahi, Rlo, accp, 0, 0, 0);
                    LOADP(R, kt + 2);  // kt=14 -> wraps to 0: next step's prefetch
                }
                {
                    bf16x8 ahi = *(const bf16x8*)&h_hi[col][(kt + 1) * 32 + quad * 8];
                    bf16x8 alo = *(const bf16x8*)&h_lo[col][(kt + 1) * 32 + quad * 8];
                    accp = __builtin_amdgcn_mfma_f32_16x16x32_bf16(ahi, Shi, accp, 0, 0, 0);
                    accp = __builtin_amdgcn_mfma_f32_16x16x32_bf16(alo, Shi, accp, 0, 0, 0);
                    accp = __builtin_amdgcn_mfma_f32_16x16x32_bf16(ahi, Slo, accp, 0, 0, 0);
                    LOADP(S, kt + 3);  // kt=14 -> wraps to 1
                }
            }
#pragma unroll
            for (int rg = 0; rg < 4; rg++)
                lgbuf[bq + rg][w * 16 + col][sl] = accp[rg] + bp;
        }
        __syncthreads();  // full logit rows visible

        // ---- P3b: argmax; wave w handles rows 2w, 2w+1
        {
#pragma unroll
            for (int pass = 0; pass < 2; pass++) {
                const int r = w * 2 + pass;
                float v0 = lgbuf[r][lane][sl];
                float v1 = lgbuf[r][lane + 64][sl];
                float bv; int bi;
                if (v0 >= v1) { bv = v0; bi = lane; } else { bv = v1; bi = lane + 64; }
#pragma unroll
                for (int off = 32; off > 0; off >>= 1) {
                    float ov = __shfl_down(bv, off, 64);
                    int oi = __shfl_down(bi, off, 64);
                    if (ov > bv || (ov == bv && oi < bi)) { bv = ov; bi = oi; }
                }
                if (lane == 0) {
                    tok_s[r] = bi;
                    __builtin_nontemporal_store((float)bi, &out_tok[(size_t)(row0 + r) * TT + step]);
                }
            }
        }
        __syncthreads();  // tok_s visible for next P2; lgbuf stable for flush

        // ---- flush logits every 8 steps (nontemporal: keep weights L2-resident)
        if ((step & 7) == 7 || step == TT - 1) {
            const int t0 = step & ~7;
            const int cnt = step - t0 + 1;
#pragma unroll
            for (int p = 0; p < 4; p++) {
                const int pair = t + p * 512;          // 0..2047
                const int b = pair >> 7, c = pair & (CC - 1);
                float* dst = out_logits + ((size_t)(row0 + b) * CC + c) * TT + t0;
                const float* src = &lgbuf[b][c][0];
                for (int q = 0; q < cnt; q++) __builtin_nontemporal_store(src[q], &dst[q]);
            }
        }
    }
}

// ---------------- launcher ----------------

extern "C" void kernel_launch(void* const* d_in, const int* in_sizes, int n_in,
                              void* d_out, int out_size, void* d_ws, size_t ws_size,
                              hipStream_t stream) {
    const float* feat   = (const float*)d_in[0];
    const float* W_ih   = (const float*)d_in[1];
    const float* W_hh   = (const float*)d_in[2];
    const float* b_ih   = (const float*)d_in[3];
    const float* b_hh   = (const float*)d_in[4];
    const float* W_proj = (const float*)d_in[5];
    const float* b_proj = (const float*)d_in[6];
    const float* embed  = (const float*)d_in[7];
    float* out = (float*)d_out;

    float* ws = (float*)d_ws;
    float*  WihT = ws;                         // 786432 floats
    float*  E    = ws + 786432;                // 198144 floats
    __bf16* Wpf  = (__bf16*)(ws + 984576);     // 131072 bf16 = 65536 float slots
    __bf16* Whf  = (__bf16*)(ws + 1050112);    // 1572864 bf16 = 786432 float slots
    // total: 1836544 floats = 7.3 MB

    hipLaunchKernelGGL(k_transpose_wih, dim3(3072), dim3(256), 0, stream, W_ih, WihT);
    hipLaunchKernelGGL(k_pack_wp_frag, dim3(512), dim3(256), 0, stream, W_proj, Wpf);
    hipLaunchKernelGGL(k_pack_whh_frag, dim3(3072), dim3(256), 0, stream, W_hh, Whf);
    hipLaunchKernelGGL(k_build_E, dim3(6, 9), dim3(256), 0, stream, embed, WihT, b_ih, b_hh, E);
    hipLaunchKernelGGL(k_gru, dim3(128), dim3(512), 0, stream,
                       feat, Whf, Wpf, b_proj, b_hh, E, out);
}